// Round 16
// baseline (175.921 us; speedup 1.0000x reference)
//
#include <hip/hip_runtime.h>
#include <stdint.h>

#define B_ 4
#define L_ 2048
#define D_ 1024
#define H_ 16
#define DK_ 64

typedef __attribute__((ext_vector_type(8))) short bf16x8;
typedef __attribute__((ext_vector_type(4))) float f32x4;
typedef unsigned short bfu;   // raw bf16 storage

#define MFMA(a, b, c) __builtin_amdgcn_mfma_f32_16x16x32_bf16((a), (b), (c), 0, 0, 0)

__device__ __forceinline__ unsigned short f2bf(float f) {
  union { float f; unsigned int u; } v; v.f = f;
  unsigned int u = v.u;
  return (unsigned short)((u + 0x7fffu + ((u >> 16) & 1u)) >> 16);  // RNE
}

__device__ __forceinline__ void gll16(const void* g, void* l) {
  __builtin_amdgcn_global_load_lds(
      (const __attribute__((address_space(1))) void*)g,
      (__attribute__((address_space(3))) void*)l, 16, 0, 0);
}

#define VMCNT(n_) asm volatile("s_waitcnt vmcnt(" #n_ ")" ::: "memory")
#define BARRIER() asm volatile("s_barrier" ::: "memory")

// ---------------- prep kernels ----------------

__global__ __launch_bounds__(256) void cast_x(const float* __restrict__ in,
                                              bfu* __restrict__ out, int n4) {
  int i = blockIdx.x * 256 + threadIdx.x;
  if (i >= n4) return;
  float4 v = ((const float4*)in)[i];
  ushort4 o;
  o.x = f2bf(v.x); o.y = f2bf(v.y); o.z = f2bf(v.z); o.w = f2bf(v.w);
  ((ushort4*)out)[i] = o;
}

// W[K][C] fp32 -> B-fragment-packed bf16: block (c>>4, k>>3) of 128 bfu,
// within block (c&15)*8 + (k&7).
__global__ __launch_bounds__(256) void wpack2(const float* __restrict__ in,
                                              bfu* __restrict__ out, int K, int C) {
  int idx = blockIdx.x * 256 + threadIdx.x;
  int c = idx % C, kb = idx / C;
  if (kb >= (K >> 3)) return;
  unsigned short v[8];
#pragma unroll
  for (int j = 0; j < 8; ++j) v[j] = f2bf(in[(size_t)(kb * 8 + j) * C + c]);
  size_t o = ((size_t)(c >> 4) * (K >> 3) + kb) * 128 + (c & 15) * 8;
  *(ushort4*)(out + o) = make_ushort4(v[0], v[1], v[2], v[3]);
  *(ushort4*)(out + o + 4) = make_ushort4(v[4], v[5], v[6], v[7]);
}

// ---------------- reg-B GEMM (round-11 structure, proven 68.2us) ----------
// C[M][N] = A[M][K]*B[K][N], B frag-packed. 256 thr = 4 waves (2m x 2n),
// tile 128x128, per-wave 64x64. A LDS-dbuf via gll16 (1 tile ahead), B in
// named reg buffers brA/brB (2 tiles ahead). Uniform VMCNT(8), one barrier
// per K-tile. Supertile: XCD owns 8-m-tile band, sweeps n.
// EPI 0: scatter Q (log2e/8), K, V (sigma^-1-permuted transpose via LDS).
// EPI 1: fp32 out += bias.

template <int EPI>
__global__ __launch_bounds__(256, 2) void gemm_r(
    const bfu* __restrict__ A, const bfu* __restrict__ Bp,
    const float* __restrict__ bias, bfu* __restrict__ Qg, bfu* __restrict__ Kg,
    bfu* __restrict__ Vtg, float* __restrict__ Out, int M, int N, int K) {
  __shared__ __align__(16) bfu As[2][128 * 64];  // 32 KB total
  const int tid = threadIdx.x;
  const int lane = tid & 63;
  const int w = tid >> 6;
  const int wm = w >> 1, wn = w & 1;
  const int l15 = lane & 15, l4 = lane >> 4;

  const int nwg = gridDim.x;
  const int cpx = nwg >> 3;
  const int bid = (int)blockIdx.x;
  const int swz = (bid & 7) * cpx + (bid >> 3);
  const int NTt = N / 128;
  const int m0 = ((swz & 7) + 8 * (swz / (8 * NTt))) * 128;
  const int n0 = ((swz >> 3) % NTt) * 128;
  const int K8 = K >> 3;

  auto stageA = [&](int t) {
    char* lb = (char*)As[t & 1];
#pragma unroll
    for (int j = 0; j < 4; ++j) {
      int idx = j * 256 + tid;
      int row = idx >> 3, c16p = idx & 7, c16 = c16p ^ (row & 7);
      gll16(A + (size_t)(m0 + row) * K + t * 64 + c16 * 8,
            lb + row * 128 + c16p * 16);
    }
  };

  const size_t bbase = ((size_t)((n0 + wn * 64) >> 4)) * K8;
  auto loadB = [&](int t, bf16x8 (&br)[4][2]) {
#pragma unroll
    for (int ni = 0; ni < 4; ++ni)
#pragma unroll
      for (int kk = 0; kk < 2; ++kk)
        br[ni][kk] = *(const bf16x8*)(
            Bp + (bbase + (size_t)ni * K8 + t * 8 + kk * 4 + l4) * 128 + l15 * 8);
  };

  f32x4 acc[4][4] = {};
  bf16x8 af[4][2], brA[4][2], brB[4][2];

  auto lda = [&](int t) {
    const char* base = (const char*)As[t & 1];
#pragma unroll
    for (int mi = 0; mi < 4; ++mi)
#pragma unroll
      for (int kk = 0; kk < 2; ++kk) {
        int row = wm * 64 + mi * 16 + l15;
        int ch = (kk * 4 + l4) ^ (row & 7);
        af[mi][kk] = *(const bf16x8*)(base + row * 128 + ch * 16);
      }
  };
  auto mm_all = [&](bf16x8 (&br)[4][2]) {
    __builtin_amdgcn_s_setprio(1);
#pragma unroll
    for (int kk = 0; kk < 2; ++kk)
#pragma unroll
      for (int mi = 0; mi < 4; ++mi)
#pragma unroll
        for (int ni = 0; ni < 4; ++ni)
          acc[mi][ni] = MFMA(af[mi][kk], br[ni][kk], acc[mi][ni]);
    __builtin_amdgcn_s_setprio(0);
  };

  const int NT = K >> 6;  // even
  stageA(0);
  __builtin_amdgcn_sched_barrier(0);
  loadB(0, brA);
  loadB(1, brB);

  for (int t = 0; t < NT; t += 2) {
    VMCNT(8); BARRIER();
    lda(t);
    stageA(t + 1);
    __builtin_amdgcn_sched_barrier(0);
    mm_all(brA);
    if (t + 2 < NT) loadB(t + 2, brA);
    if (t + 2 < NT) { VMCNT(8); } else { VMCNT(0); }
    BARRIER();
    lda(t + 1);
    if (t + 2 < NT) stageA(t + 2);
    __builtin_amdgcn_sched_barrier(0);
    mm_all(brB);
    if (t + 3 < NT) loadB(t + 3, brB);
  }

  // ---- epilogue: C/D layout col = lane&15, row = (lane>>4)*4 + reg
  if constexpr (EPI == 1) {
#pragma unroll
    for (int ni = 0; ni < 4; ++ni) {
      int gn = n0 + wn * 64 + ni * 16 + l15;
      float bv = bias[gn];
#pragma unroll
      for (int mi = 0; mi < 4; ++mi)
#pragma unroll
        for (int rg = 0; rg < 4; ++rg) {
          int gm = m0 + wm * 64 + mi * 16 + l4 * 4 + rg;
          Out[(size_t)gm * N + gn] = acc[mi][ni][rg] + bv;
        }
    }
  } else {
    const int sec = n0 >> 10;  // 0 Q, 1 K, 2 V (1024-wide sections)
    if (sec < 2) {
      bfu* dst = (sec == 0) ? Qg : Kg;
      const float scale = (sec == 0) ? 0.18033688011112042f : 1.0f;  // log2e/8
#pragma unroll
      for (int ni = 0; ni < 4; ++ni) {
        int gn = n0 + wn * 64 + ni * 16 + l15;
        int rem = gn & 1023;
        int hh = rem >> 6, dk = rem & 63;
        float bv = bias[gn];
#pragma unroll
        for (int mi = 0; mi < 4; ++mi)
#pragma unroll
          for (int rg = 0; rg < 4; ++rg) {
            int gm = m0 + wm * 64 + mi * 16 + l4 * 4 + rg;
            int bb = gm >> 11, ll = gm & 2047;
            dst[(((size_t)(bb * H_ + hh)) * L_ + ll) * DK_ + dk] =
                f2bf((acc[mi][ni][rg] + bv) * scale);
          }
      }
    } else {
      // V: sigma^-1-permuted transpose via LDS (128n x 128m x 2B = 32 KB)
      __syncthreads();
#pragma unroll
      for (int ni = 0; ni < 4; ++ni) {
        int n_local = wn * 64 + ni * 16 + l15;
        int gn = n0 + n_local;
        float bv = bias[gn];
        int swzn = (n_local & 7) << 4;
#pragma unroll
        for (int mi = 0; mi < 4; ++mi) {
          int m_base = wm * 64 + mi * 16 + l4 * 4;
          int k6 = m_base & 63;
          int p0 = (m_base & ~63) |
                   ((k6 & 32) | (((k6 >> 2) & 3) << 3) | (((k6 >> 4) & 1) << 2));
          float v0 = acc[mi][ni][0] + bv, v1 = acc[mi][ni][1] + bv;
          float v2 = acc[mi][ni][2] + bv, v3 = acc[mi][ni][3] + bv;
          uint32_t w01, w23;
          asm("v_cvt_pk_bf16_f32 %0, %1, %2" : "=v"(w01) : "v"(v0), "v"(v1));
          asm("v_cvt_pk_bf16_f32 %0, %1, %2" : "=v"(w23) : "v"(v2), "v"(v3));
          *(uint32_t*)((char*)As + n_local * 256 + ((2 * p0) ^ swzn)) = w01;
          *(uint32_t*)((char*)As + n_local * 256 + ((2 * p0 + 4) ^ swzn)) = w23;
        }
      }
      __syncthreads();
      int n = tid >> 1;            // 2 threads per n-row
      int cb = (tid & 1) * 8;      // 8 x 16B chunks each
      int gnn = n0 + n;
      int hh = (gnn >> 6) & 15, dk = gnn & 63;
      size_t rowbase =
          (((size_t)((m0 >> 11) * H_ + hh)) * DK_ + dk) * L_ + (m0 & 2047);
#pragma unroll
      for (int j = 0; j < 8; ++j) {
        int ch = cb + j;
        bf16x8 vv = *(const bf16x8*)((char*)As + n * 256 +
                                     ((ch * 16) ^ ((n & 7) << 4)));
        *(bf16x8*)(Vtg + rowbase + ch * 8) = vv;
      }
    }
  }
}

// ---------------- flash attention v7 (causal) ----------------
// = v6 body, but 1024 blocks (3 blocks/CU resident; was grid-limited to 2).
// XCD clustering KEPT: xcd = hid&7, bh = xcd*8 + (slot>>4) -> 8 bh per XCD
// (K/V L2-resident, the r13 failure cause #1); triple-buffered K/V with
// vmcnt(8) 2-tile slack (failure cause #2). qb = 15-(slot&15): longest
// blocks dispatch first so backfill balances the causal imbalance.

__global__ __launch_bounds__(256, 3) void attn(const bfu* __restrict__ Qg,
                                               const bfu* __restrict__ Kg,
                                               const bfu* __restrict__ Vtg,
                                               bfu* __restrict__ Ao) {
  __shared__ __align__(16) bfu Ks[3 * 64 * 64];  // 24 KB
  __shared__ __align__(16) bfu Vs[3 * 64 * 64];  // 24 KB

  const int tid = threadIdx.x;
  const int lane = tid & 63;
  const int w = tid >> 6;
  const int l15 = lane & 15, l4 = lane >> 4;

  const int hid = blockIdx.x;            // 1024 blocks
  const int xcd = hid & 7, slot = hid >> 3;   // slot in [0,128)
  const int bh = xcd * 8 + (slot >> 4);  // 8 bh per XCD
  const int qb = 15 - (slot & 15);       // long blocks first
  const int b = bh >> 4, h = bh & 15;

  const int q0 = qb * 128;
  const int nt = 2 * qb + 2;
  const int q0w = q0 + w * 32;           // wave's first q row

  // ---- Q fragments straight from global (Qg pre-scaled by log2e/8)
  bf16x8 qf[2][2];
#pragma unroll
  for (int mi = 0; mi < 2; ++mi)
#pragma unroll
    for (int kk = 0; kk < 2; ++kk)
      qf[mi][kk] = *(const bf16x8*)(
          Qg + ((size_t)bh * L_ + q0w + mi * 16 + l15) * DK_ + kk * 32 + l4 * 8);

  auto stageKV = [&](int tt) {
    const int nb = tt % 3;
    const int nkv = tt * 64;
#pragma unroll
    for (int i = 0; i < 2; ++i) {
      int lb = i * 256 + tid;
      int rr = lb >> 3, c16 = (lb & 7) ^ (rr & 7);
      gll16(Kg + ((size_t)bh * L_ + nkv + rr) * DK_ + c16 * 8,
            (char*)Ks + nb * 8192 + lb * 16);
      gll16(Vtg + ((size_t)bh * DK_ + rr) * L_ + nkv + c16 * 8,
            (char*)Vs + nb * 8192 + lb * 16);
    }
  };

  // ---- prologue: stage tiles 0,1 then FULL drain (order-independent)
  stageKV(0);
  stageKV(1);          // nt >= 2 always
  VMCNT(0);
  BARRIER();

  f32x4 acco[2][4] = {};
  float m[2] = {-1e30f, -1e30f};  // per-lane running max (q = l15)
  float l[2] = {0.f, 0.f};

  for (int t = 0; t < nt; ++t) {
    const int cur = t % 3;
    const int kv0 = t * 64;
    const char* Kc = (const char*)Ks + cur * 8192;
    const char* Vc = (const char*)Vs + cur * 8192;

    // waits (post-drain accounting): steady VMCNT(8) retires s(t);
    // t=nt-2: VMCNT(4); t=nt-1: VMCNT(0).
    if (t + 2 < nt) {
      stageKV(t + 2);
      VMCNT(8);
    } else if (t + 1 < nt) {
      VMCNT(4);
    } else {
      VMCNT(0);
    }
    BARRIER();

    if (kv0 <= q0w + 31) {  // wave has unmasked rows in this tile
      // ---- S^T = K Q^T : s[mi][ni][rg] = S^T[kv=ni*16+l4*4+rg][q=l15]
      f32x4 s[2][4] = {};
      __builtin_amdgcn_s_setprio(1);
#pragma unroll
      for (int kk = 0; kk < 2; ++kk)
#pragma unroll
        for (int ni = 0; ni < 4; ++ni) {
          int rr = ni * 16 + l15;
          int ch = (kk * 4 + l4) ^ (rr & 7);
          bf16x8 kf = *(const bf16x8*)(Kc + rr * 128 + ch * 16);
#pragma unroll
          for (int mi = 0; mi < 2; ++mi)
            s[mi][ni] = MFMA(kf, qf[mi][kk], s[mi][ni]);
        }
      __builtin_amdgcn_s_setprio(0);

      if (kv0 + 63 > q0w) {  // diagonal band: mask kv > q
#pragma unroll
        for (int mi = 0; mi < 2; ++mi) {
          int qg_ = q0w + mi * 16 + l15;
#pragma unroll
          for (int ni = 0; ni < 4; ++ni) {
            int kvg = kv0 + ni * 16 + l4 * 4;
#pragma unroll
            for (int rg = 0; rg < 4; ++rg)
              if (kvg + rg > qg_) s[mi][ni][rg] = -1e30f;
          }
        }
      }

      // ---- row max (max3-shaped tree) + defer-max rescale
      float mx[2];
#pragma unroll
      for (int mi = 0; mi < 2; ++mi) {
        float t1 = fmaxf(fmaxf(s[mi][0][0], s[mi][0][1]), s[mi][0][2]);
        float t2 = fmaxf(fmaxf(s[mi][0][3], s[mi][1][0]), s[mi][1][1]);
        float t3 = fmaxf(fmaxf(s[mi][1][2], s[mi][1][3]), s[mi][2][0]);
        float t4 = fmaxf(fmaxf(s[mi][2][1], s[mi][2][2]), s[mi][2][3]);
        float t5 = fmaxf(fmaxf(s[mi][3][0], s[mi][3][1]), s[mi][3][2]);
        float v = fmaxf(fmaxf(t1, t2), t3);
        v = fmaxf(fmaxf(v, t4), fmaxf(t5, s[mi][3][3]));
        v = fmaxf(v, __shfl_xor(v, 16));
        v = fmaxf(v, __shfl_xor(v, 32));
        mx[mi] = v;
      }
      float grow = fmaxf(mx[0] - m[0], mx[1] - m[1]);
      if (__any(grow > 11.0f)) {
#pragma unroll
        for (int mi = 0; mi < 2; ++mi) {
          float mn = fmaxf(m[mi], mx[mi]);
          float sc = __builtin_amdgcn_exp2f(m[mi] - mn);
          m[mi] = mn;
          l[mi] *= sc;
#pragma unroll
          for (int rg = 0; rg < 4; ++rg) {
            float scq = __shfl(sc, l4 * 4 + rg);
            acco[mi][0][rg] *= scq; acco[mi][1][rg] *= scq;
            acco[mi][2][rg] *= scq; acco[mi][3][rg] *= scq;
          }
        }
      }

      // ---- P = exp2(S^T - m), pack bf16 pairs (kv ascending)
      uint32_t pk[2][4][2];
#pragma unroll
      for (int mi = 0; mi < 2; ++mi)
#pragma unroll
        for (int ni = 0; ni < 4; ++ni) {
          float p0 = __builtin_amdgcn_exp2f(s[mi][ni][0] - m[mi]);
          float p1 = __builtin_amdgcn_exp2f(s[mi][ni][1] - m[mi]);
          float p2 = __builtin_amdgcn_exp2f(s[mi][ni][2] - m[mi]);
          float p3 = __builtin_amdgcn_exp2f(s[mi][ni][3] - m[mi]);
          l[mi] += (p0 + p1) + (p2 + p3);
          asm("v_cvt_pk_bf16_f32 %0, %1, %2" : "=v"(pk[mi][ni][0]) : "v"(p0), "v"(p1));
          asm("v_cvt_pk_bf16_f32 %0, %1, %2" : "=v"(pk[mi][ni][1]) : "v"(p2), "v"(p3));
        }

      // ---- O += P V : pk words ARE the A-frag (V kv-cols pre-permuted)
      __builtin_amdgcn_s_setprio(1);
#pragma unroll
      for (int kk = 0; kk < 2; ++kk) {
        union { uint32_t wd[4]; bf16x8 v; } u[2];
#pragma unroll
        for (int mi = 0; mi < 2; ++mi) {
          u[mi].wd[0] = pk[mi][2 * kk][0];
          u[mi].wd[1] = pk[mi][2 * kk][1];
          u[mi].wd[2] = pk[mi][2 * kk + 1][0];
          u[mi].wd[3] = pk[mi][2 * kk + 1][1];
        }
#pragma unroll
        for (int ni = 0; ni < 4; ++ni) {
          int rr = ni * 16 + l15;
          int ch = (kk * 4 + l4) ^ (rr & 7);
          bf16x8 vf = *(const bf16x8*)(Vc + rr * 128 + ch * 16);
#pragma unroll
          for (int mi = 0; mi < 2; ++mi)
            acco[mi][ni] = MFMA(u[mi].v, vf, acco[mi][ni]);
        }
      }
      __builtin_amdgcn_s_setprio(0);
    }  // active wave

    BARRIER();  // all waves done with buf[cur]
  }

  // ---- epilogue: reduce l across l4, redistribute to acco rows, write O
#pragma unroll
  for (int mi = 0; mi < 2; ++mi) {
    float ls = l[mi];
    ls += __shfl_xor(ls, 16);
    ls += __shfl_xor(ls, 32);
    float linv = 1.0f / ls;
#pragma unroll
    for (int rg = 0; rg < 4; ++rg) {
      float lq = __shfl(linv, l4 * 4 + rg);
      int q = q0w + mi * 16 + l4 * 4 + rg;
#pragma unroll
      for (int ni = 0; ni < 4; ++ni) {
        int d = ni * 16 + l15;
        Ao[((size_t)b * L_ + q) * D_ + h * DK_ + d] = f2bf(acco[mi][ni][rg] * lq);
      }
    }
  }
}

// ---------------- launch ----------------

extern "C" void kernel_launch(void* const* d_in, const int* in_sizes, int n_in,
                              void* d_out, int out_size, void* d_ws, size_t ws_size,
                              hipStream_t stream) {
  const float* x = (const float*)d_in[0];
  const float* W_qkv = (const float*)d_in[1];
  const float* b_qkv = (const float*)d_in[2];
  const float* W_out = (const float*)d_in[3];
  const float* b_out = (const float*)d_in[4];
  float* out = (float*)d_out;

  char* ws = (char*)d_ws;
  bfu* xb     = (bfu*)(ws);                    // 16,777,216
  bfu* Wqkv_p = (bfu*)(ws + 16777216);         //  6,291,456
  bfu* Wout_p = (bfu*)(ws + 23068672);         //  2,097,152
  bfu* Qg     = (bfu*)(ws + 25165824);         // 16,777,216
  bfu* Kg     = (bfu*)(ws + 41943040);         // 16,777,216
  bfu* Vtg    = (bfu*)(ws + 58720256);         // 16,777,216
  bfu* Ao     = (bfu*)(ws + 75497472);         // 16,777,216

  cast_x<<<8192, 256, 0, stream>>>(x, xb, 2097152);
  wpack2<<<1536, 256, 0, stream>>>(W_qkv, Wqkv_p, 1024, 3072);
  wpack2<<<512, 256, 0, stream>>>(W_out, Wout_p, 1024, 1024);

  // gemm0: 128x128 tiles, grid 64m x 24n = 1536, 2 blocks/CU
  gemm_r<0><<<1536, 256, 0, stream>>>(xb, Wqkv_p, b_qkv, Qg, Kg, Vtg, nullptr,
                                      8192, 3072, 1024);
  attn<<<1024, 256, 0, stream>>>(Qg, Kg, Vtg, Ao);
  // gemm1: 128x128 tiles, grid 64m x 8n = 512
  gemm_r<1><<<512, 256, 0, stream>>>(Ao, Wout_p, b_out, nullptr, nullptr, nullptr,
                                     out, 8192, 1024, 1024);
}

// Round 17
// 160.062 us; speedup vs baseline: 1.0991x; 1.0991x over previous
//
#include <hip/hip_runtime.h>
#include <stdint.h>

#define B_ 4
#define L_ 2048
#define D_ 1024
#define H_ 16
#define DK_ 64

typedef __attribute__((ext_vector_type(8))) short bf16x8;
typedef __attribute__((ext_vector_type(4))) float f32x4;
typedef unsigned short bfu;   // raw bf16 storage

#define MFMA(a, b, c) __builtin_amdgcn_mfma_f32_16x16x32_bf16((a), (b), (c), 0, 0, 0)

__device__ __forceinline__ unsigned short f2bf(float f) {
  union { float f; unsigned int u; } v; v.f = f;
  unsigned int u = v.u;
  return (unsigned short)((u + 0x7fffu + ((u >> 16) & 1u)) >> 16);  // RNE
}

__device__ __forceinline__ void gll16(const void* g, void* l) {
  __builtin_amdgcn_global_load_lds(
      (const __attribute__((address_space(1))) void*)g,
      (__attribute__((address_space(3))) void*)l, 16, 0, 0);
}

#define VMCNT(n_) asm volatile("s_waitcnt vmcnt(" #n_ ")" ::: "memory")
#define BARRIER() asm volatile("s_barrier" ::: "memory")

// ---------------- prep kernels ----------------

__global__ __launch_bounds__(256) void cast_x(const float* __restrict__ in,
                                              bfu* __restrict__ out, int n4) {
  int i = blockIdx.x * 256 + threadIdx.x;
  if (i >= n4) return;
  float4 v = ((const float4*)in)[i];
  ushort4 o;
  o.x = f2bf(v.x); o.y = f2bf(v.y); o.z = f2bf(v.z); o.w = f2bf(v.w);
  ((ushort4*)out)[i] = o;
}

// W[K][C] fp32 -> B-fragment-packed bf16: block (c>>4, k>>3) of 128 bfu,
// within block (c&15)*8 + (k&7).
__global__ __launch_bounds__(256) void wpack2(const float* __restrict__ in,
                                              bfu* __restrict__ out, int K, int C) {
  int idx = blockIdx.x * 256 + threadIdx.x;
  int c = idx % C, kb = idx / C;
  if (kb >= (K >> 3)) return;
  unsigned short v[8];
#pragma unroll
  for (int j = 0; j < 8; ++j) v[j] = f2bf(in[(size_t)(kb * 8 + j) * C + c]);
  size_t o = ((size_t)(c >> 4) * (K >> 3) + kb) * 128 + (c & 15) * 8;
  *(ushort4*)(out + o) = make_ushort4(v[0], v[1], v[2], v[3]);
  *(ushort4*)(out + o + 4) = make_ushort4(v[4], v[5], v[6], v[7]);
}

// ---------------- reg-B GEMM (round-11 structure, proven 68.2us) ----------
// C[M][N] = A[M][K]*B[K][N], B frag-packed. 256 thr = 4 waves (2m x 2n),
// tile 128x128, per-wave 64x64. A LDS-dbuf via gll16 (1 tile ahead), B in
// named reg buffers brA/brB (2 tiles ahead). Uniform VMCNT(8), one barrier
// per K-tile. Supertile: XCD owns 8-m-tile band, sweeps n.
// EPI 0: scatter Q (log2e/8), K, V (sigma^-1-permuted transpose via LDS).
// EPI 1: fp32 out += bias.

template <int EPI>
__global__ __launch_bounds__(256, 2) void gemm_r(
    const bfu* __restrict__ A, const bfu* __restrict__ Bp,
    const float* __restrict__ bias, bfu* __restrict__ Qg, bfu* __restrict__ Kg,
    bfu* __restrict__ Vtg, float* __restrict__ Out, int M, int N, int K) {
  __shared__ __align__(16) bfu As[2][128 * 64];  // 32 KB total
  const int tid = threadIdx.x;
  const int lane = tid & 63;
  const int w = tid >> 6;
  const int wm = w >> 1, wn = w & 1;
  const int l15 = lane & 15, l4 = lane >> 4;

  const int nwg = gridDim.x;
  const int cpx = nwg >> 3;
  const int bid = (int)blockIdx.x;
  const int swz = (bid & 7) * cpx + (bid >> 3);
  const int NTt = N / 128;
  const int m0 = ((swz & 7) + 8 * (swz / (8 * NTt))) * 128;
  const int n0 = ((swz >> 3) % NTt) * 128;
  const int K8 = K >> 3;

  auto stageA = [&](int t) {
    char* lb = (char*)As[t & 1];
#pragma unroll
    for (int j = 0; j < 4; ++j) {
      int idx = j * 256 + tid;
      int row = idx >> 3, c16p = idx & 7, c16 = c16p ^ (row & 7);
      gll16(A + (size_t)(m0 + row) * K + t * 64 + c16 * 8,
            lb + row * 128 + c16p * 16);
    }
  };

  const size_t bbase = ((size_t)((n0 + wn * 64) >> 4)) * K8;
  auto loadB = [&](int t, bf16x8 (&br)[4][2]) {
#pragma unroll
    for (int ni = 0; ni < 4; ++ni)
#pragma unroll
      for (int kk = 0; kk < 2; ++kk)
        br[ni][kk] = *(const bf16x8*)(
            Bp + (bbase + (size_t)ni * K8 + t * 8 + kk * 4 + l4) * 128 + l15 * 8);
  };

  f32x4 acc[4][4] = {};
  bf16x8 af[4][2], brA[4][2], brB[4][2];

  auto lda = [&](int t) {
    const char* base = (const char*)As[t & 1];
#pragma unroll
    for (int mi = 0; mi < 4; ++mi)
#pragma unroll
      for (int kk = 0; kk < 2; ++kk) {
        int row = wm * 64 + mi * 16 + l15;
        int ch = (kk * 4 + l4) ^ (row & 7);
        af[mi][kk] = *(const bf16x8*)(base + row * 128 + ch * 16);
      }
  };
  auto mm_all = [&](bf16x8 (&br)[4][2]) {
    __builtin_amdgcn_s_setprio(1);
#pragma unroll
    for (int kk = 0; kk < 2; ++kk)
#pragma unroll
      for (int mi = 0; mi < 4; ++mi)
#pragma unroll
        for (int ni = 0; ni < 4; ++ni)
          acc[mi][ni] = MFMA(af[mi][kk], br[ni][kk], acc[mi][ni]);
    __builtin_amdgcn_s_setprio(0);
  };

  const int NT = K >> 6;  // even
  stageA(0);
  __builtin_amdgcn_sched_barrier(0);
  loadB(0, brA);
  loadB(1, brB);

  for (int t = 0; t < NT; t += 2) {
    VMCNT(8); BARRIER();
    lda(t);
    stageA(t + 1);
    __builtin_amdgcn_sched_barrier(0);
    mm_all(brA);
    if (t + 2 < NT) loadB(t + 2, brA);
    if (t + 2 < NT) { VMCNT(8); } else { VMCNT(0); }
    BARRIER();
    lda(t + 1);
    if (t + 2 < NT) stageA(t + 2);
    __builtin_amdgcn_sched_barrier(0);
    mm_all(brB);
    if (t + 3 < NT) loadB(t + 3, brB);
  }

  // ---- epilogue: C/D layout col = lane&15, row = (lane>>4)*4 + reg
  if constexpr (EPI == 1) {
#pragma unroll
    for (int ni = 0; ni < 4; ++ni) {
      int gn = n0 + wn * 64 + ni * 16 + l15;
      float bv = bias[gn];
#pragma unroll
      for (int mi = 0; mi < 4; ++mi)
#pragma unroll
        for (int rg = 0; rg < 4; ++rg) {
          int gm = m0 + wm * 64 + mi * 16 + l4 * 4 + rg;
          Out[(size_t)gm * N + gn] = acc[mi][ni][rg] + bv;
        }
    }
  } else {
    const int sec = n0 >> 10;  // 0 Q, 1 K, 2 V (1024-wide sections)
    if (sec < 2) {
      bfu* dst = (sec == 0) ? Qg : Kg;
      const float scale = (sec == 0) ? 0.18033688011112042f : 1.0f;  // log2e/8
#pragma unroll
      for (int ni = 0; ni < 4; ++ni) {
        int gn = n0 + wn * 64 + ni * 16 + l15;
        int rem = gn & 1023;
        int hh = rem >> 6, dk = rem & 63;
        float bv = bias[gn];
#pragma unroll
        for (int mi = 0; mi < 4; ++mi)
#pragma unroll
          for (int rg = 0; rg < 4; ++rg) {
            int gm = m0 + wm * 64 + mi * 16 + l4 * 4 + rg;
            int bb = gm >> 11, ll = gm & 2047;
            dst[(((size_t)(bb * H_ + hh)) * L_ + ll) * DK_ + dk] =
                f2bf((acc[mi][ni][rg] + bv) * scale);
          }
      }
    } else {
      // V: sigma^-1-permuted transpose via LDS (128n x 128m x 2B = 32 KB)
      __syncthreads();
#pragma unroll
      for (int ni = 0; ni < 4; ++ni) {
        int n_local = wn * 64 + ni * 16 + l15;
        int gn = n0 + n_local;
        float bv = bias[gn];
        int swzn = (n_local & 7) << 4;
#pragma unroll
        for (int mi = 0; mi < 4; ++mi) {
          int m_base = wm * 64 + mi * 16 + l4 * 4;
          int k6 = m_base & 63;
          int p0 = (m_base & ~63) |
                   ((k6 & 32) | (((k6 >> 2) & 3) << 3) | (((k6 >> 4) & 1) << 2));
          float v0 = acc[mi][ni][0] + bv, v1 = acc[mi][ni][1] + bv;
          float v2 = acc[mi][ni][2] + bv, v3 = acc[mi][ni][3] + bv;
          uint32_t w01, w23;
          asm("v_cvt_pk_bf16_f32 %0, %1, %2" : "=v"(w01) : "v"(v0), "v"(v1));
          asm("v_cvt_pk_bf16_f32 %0, %1, %2" : "=v"(w23) : "v"(v2), "v"(v3));
          *(uint32_t*)((char*)As + n_local * 256 + ((2 * p0) ^ swzn)) = w01;
          *(uint32_t*)((char*)As + n_local * 256 + ((2 * p0 + 4) ^ swzn)) = w23;
        }
      }
      __syncthreads();
      int n = tid >> 1;            // 2 threads per n-row
      int cb = (tid & 1) * 8;      // 8 x 16B chunks each
      int gnn = n0 + n;
      int hh = (gnn >> 6) & 15, dk = gnn & 63;
      size_t rowbase =
          (((size_t)((m0 >> 11) * H_ + hh)) * DK_ + dk) * L_ + (m0 & 2047);
#pragma unroll
      for (int j = 0; j < 8; ++j) {
        int ch = cb + j;
        bf16x8 vv = *(const bf16x8*)((char*)As + n * 256 +
                                     ((ch * 16) ^ ((n & 7) << 4)));
        *(bf16x8*)(Vtg + rowbase + ch * 8) = vv;
      }
    }
  }
}

// ---------------- flash attention v6 (causal) — proven 160.5us ensemble ----
// 512 blocks; xcd = hid&7, 8 bh per XCD. Block handles superblocks
// {p, 15-p} (34 KV tiles, perfect balance, all blocks finish together).
// 4 waves; wave owns 32 q rows. Q direct to regs; S^T = mfma(K,Q);
// V sigma-permuted so packed P words ARE the PV A-fragment. Triple-buffered
// K/V with vmcnt(8) 2-tile slack; prologue full drain (order-independent).

__global__ __launch_bounds__(256, 3) void attn(const bfu* __restrict__ Qg,
                                               const bfu* __restrict__ Kg,
                                               const bfu* __restrict__ Vtg,
                                               bfu* __restrict__ Ao) {
  __shared__ __align__(16) bfu Ks[3 * 64 * 64];  // 24 KB
  __shared__ __align__(16) bfu Vs[3 * 64 * 64];  // 24 KB

  const int tid = threadIdx.x;
  const int lane = tid & 63;
  const int w = tid >> 6;
  const int l15 = lane & 15, l4 = lane >> 4;

  const int hid = blockIdx.x;            // 512 blocks
  const int xcd = hid & 7, slot = hid >> 3;
  const int bh = xcd * 8 + (slot >> 3);  // 8 bh per XCD
  const int p = slot & 7;
  const int b = bh >> 4, h = bh & 15;

  for (int seg = 0; seg < 2; ++seg) {
    const int qb = (seg == 0) ? p : 15 - p;   // 128-row superblock
    const int q0 = qb * 128;
    const int nt = 2 * qb + 2;
    const int q0w = q0 + w * 32;              // wave's first q row

    // ---- Q fragments straight from global (Qg pre-scaled by log2e/8)
    bf16x8 qf[2][2];
#pragma unroll
    for (int mi = 0; mi < 2; ++mi)
#pragma unroll
      for (int kk = 0; kk < 2; ++kk)
        qf[mi][kk] = *(const bf16x8*)(
            Qg + ((size_t)bh * L_ + q0w + mi * 16 + l15) * DK_ + kk * 32 + l4 * 8);

    auto stageKV = [&](int tt) {
      const int nb = tt % 3;
      const int nkv = tt * 64;
#pragma unroll
      for (int i = 0; i < 2; ++i) {
        int lb = i * 256 + tid;
        int rr = lb >> 3, c16 = (lb & 7) ^ (rr & 7);
        gll16(Kg + ((size_t)bh * L_ + nkv + rr) * DK_ + c16 * 8,
              (char*)Ks + nb * 8192 + lb * 16);
        gll16(Vtg + ((size_t)bh * DK_ + rr) * L_ + nkv + c16 * 8,
              (char*)Vs + nb * 8192 + lb * 16);
      }
    };

    // ---- prologue: stage tiles 0,1 then FULL drain (order-independent)
    stageKV(0);
    stageKV(1);          // nt >= 2 always
    VMCNT(0);
    BARRIER();

    f32x4 acco[2][4] = {};
    float m[2] = {-1e30f, -1e30f};  // per-lane running max (q = l15)
    float l[2] = {0.f, 0.f};

    for (int t = 0; t < nt; ++t) {
      const int cur = t % 3;
      const int kv0 = t * 64;
      const char* Kc = (const char*)Ks + cur * 8192;
      const char* Vc = (const char*)Vs + cur * 8192;

      // waits (post-drain accounting): steady VMCNT(8) retires s(t);
      // t=nt-2: VMCNT(4) retires s(nt-2); t=nt-1: VMCNT(0).
      if (t + 2 < nt) {
        stageKV(t + 2);
        VMCNT(8);
      } else if (t + 1 < nt) {
        VMCNT(4);
      } else {
        VMCNT(0);
      }
      BARRIER();

      if (kv0 <= q0w + 31) {  // wave has unmasked rows in this tile
        // ---- S^T = K Q^T : s[mi][ni][rg] = S^T[kv=ni*16+l4*4+rg][q=l15]
        f32x4 s[2][4] = {};
        __builtin_amdgcn_s_setprio(1);
#pragma unroll
        for (int kk = 0; kk < 2; ++kk)
#pragma unroll
          for (int ni = 0; ni < 4; ++ni) {
            int rr = ni * 16 + l15;
            int ch = (kk * 4 + l4) ^ (rr & 7);
            bf16x8 kf = *(const bf16x8*)(Kc + rr * 128 + ch * 16);
#pragma unroll
            for (int mi = 0; mi < 2; ++mi)
              s[mi][ni] = MFMA(kf, qf[mi][kk], s[mi][ni]);
          }
        __builtin_amdgcn_s_setprio(0);

        if (kv0 + 63 > q0w) {  // diagonal band: mask kv > q
#pragma unroll
          for (int mi = 0; mi < 2; ++mi) {
            int qg_ = q0w + mi * 16 + l15;
#pragma unroll
            for (int ni = 0; ni < 4; ++ni) {
              int kvg = kv0 + ni * 16 + l4 * 4;
#pragma unroll
              for (int rg = 0; rg < 4; ++rg)
                if (kvg + rg > qg_) s[mi][ni][rg] = -1e30f;
            }
          }
        }

        // ---- row max (max3-shaped tree) + defer-max rescale
        float mx[2];
#pragma unroll
        for (int mi = 0; mi < 2; ++mi) {
          float t1 = fmaxf(fmaxf(s[mi][0][0], s[mi][0][1]), s[mi][0][2]);
          float t2 = fmaxf(fmaxf(s[mi][0][3], s[mi][1][0]), s[mi][1][1]);
          float t3 = fmaxf(fmaxf(s[mi][1][2], s[mi][1][3]), s[mi][2][0]);
          float t4 = fmaxf(fmaxf(s[mi][2][1], s[mi][2][2]), s[mi][2][3]);
          float t5 = fmaxf(fmaxf(s[mi][3][0], s[mi][3][1]), s[mi][3][2]);
          float v = fmaxf(fmaxf(t1, t2), t3);
          v = fmaxf(fmaxf(v, t4), fmaxf(t5, s[mi][3][3]));
          v = fmaxf(v, __shfl_xor(v, 16));
          v = fmaxf(v, __shfl_xor(v, 32));
          mx[mi] = v;
        }
        float grow = fmaxf(mx[0] - m[0], mx[1] - m[1]);
        if (__any(grow > 11.0f)) {
#pragma unroll
          for (int mi = 0; mi < 2; ++mi) {
            float mn = fmaxf(m[mi], mx[mi]);
            float sc = __builtin_amdgcn_exp2f(m[mi] - mn);
            m[mi] = mn;
            l[mi] *= sc;
#pragma unroll
            for (int rg = 0; rg < 4; ++rg) {
              float scq = __shfl(sc, l4 * 4 + rg);
              acco[mi][0][rg] *= scq; acco[mi][1][rg] *= scq;
              acco[mi][2][rg] *= scq; acco[mi][3][rg] *= scq;
            }
          }
        }

        // ---- P = exp2(S^T - m), pack bf16 pairs (kv ascending)
        uint32_t pk[2][4][2];
#pragma unroll
        for (int mi = 0; mi < 2; ++mi)
#pragma unroll
          for (int ni = 0; ni < 4; ++ni) {
            float p0 = __builtin_amdgcn_exp2f(s[mi][ni][0] - m[mi]);
            float p1 = __builtin_amdgcn_exp2f(s[mi][ni][1] - m[mi]);
            float p2 = __builtin_amdgcn_exp2f(s[mi][ni][2] - m[mi]);
            float p3 = __builtin_amdgcn_exp2f(s[mi][ni][3] - m[mi]);
            l[mi] += (p0 + p1) + (p2 + p3);
            asm("v_cvt_pk_bf16_f32 %0, %1, %2" : "=v"(pk[mi][ni][0]) : "v"(p0), "v"(p1));
            asm("v_cvt_pk_bf16_f32 %0, %1, %2" : "=v"(pk[mi][ni][1]) : "v"(p2), "v"(p3));
          }

        // ---- O += P V : pk words ARE the A-frag (V kv-cols pre-permuted)
        __builtin_amdgcn_s_setprio(1);
#pragma unroll
        for (int kk = 0; kk < 2; ++kk) {
          union { uint32_t wd[4]; bf16x8 v; } u[2];
#pragma unroll
          for (int mi = 0; mi < 2; ++mi) {
            u[mi].wd[0] = pk[mi][2 * kk][0];
            u[mi].wd[1] = pk[mi][2 * kk][1];
            u[mi].wd[2] = pk[mi][2 * kk + 1][0];
            u[mi].wd[3] = pk[mi][2 * kk + 1][1];
          }
#pragma unroll
          for (int ni = 0; ni < 4; ++ni) {
            int rr = ni * 16 + l15;
            int ch = (kk * 4 + l4) ^ (rr & 7);
            bf16x8 vf = *(const bf16x8*)(Vc + rr * 128 + ch * 16);
#pragma unroll
            for (int mi = 0; mi < 2; ++mi)
              acco[mi][ni] = MFMA(u[mi].v, vf, acco[mi][ni]);
          }
        }
        __builtin_amdgcn_s_setprio(0);
      }  // active wave

      BARRIER();  // all waves done with buf[cur]
    }

    // ---- epilogue: reduce l across l4, redistribute to acco rows, write O
#pragma unroll
    for (int mi = 0; mi < 2; ++mi) {
      float ls = l[mi];
      ls += __shfl_xor(ls, 16);
      ls += __shfl_xor(ls, 32);
      float linv = 1.0f / ls;
#pragma unroll
      for (int rg = 0; rg < 4; ++rg) {
        float lq = __shfl(linv, l4 * 4 + rg);
        int q = q0w + mi * 16 + l4 * 4 + rg;
#pragma unroll
        for (int ni = 0; ni < 4; ++ni) {
          int d = ni * 16 + l15;
          Ao[((size_t)b * L_ + q) * D_ + h * DK_ + d] = f2bf(acco[mi][ni][rg] * lq);
        }
      }
    }
  }  // seg
}

// ---------------- launch ----------------

extern "C" void kernel_launch(void* const* d_in, const int* in_sizes, int n_in,
                              void* d_out, int out_size, void* d_ws, size_t ws_size,
                              hipStream_t stream) {
  const float* x = (const float*)d_in[0];
  const float* W_qkv = (const float*)d_in[1];
  const float* b_qkv = (const float*)d_in[2];
  const float* W_out = (const float*)d_in[3];
  const float* b_out = (const float*)d_in[4];
  float* out = (float*)d_out;

  char* ws = (char*)d_ws;
  bfu* xb     = (bfu*)(ws);                    // 16,777,216
  bfu* Wqkv_p = (bfu*)(ws + 16777216);         //  6,291,456
  bfu* Wout_p = (bfu*)(ws + 23068672);         //  2,097,152
  bfu* Qg     = (bfu*)(ws + 25165824);         // 16,777,216
  bfu* Kg     = (bfu*)(ws + 41943040);         // 16,777,216
  bfu* Vtg    = (bfu*)(ws + 58720256);         // 16,777,216
  bfu* Ao     = (bfu*)(ws + 75497472);         // 16,777,216

  cast_x<<<8192, 256, 0, stream>>>(x, xb, 2097152);
  wpack2<<<1536, 256, 0, stream>>>(W_qkv, Wqkv_p, 1024, 3072);
  wpack2<<<512, 256, 0, stream>>>(W_out, Wout_p, 1024, 1024);

  // gemm0: 128x128 tiles, grid 64m x 24n = 1536, 2 blocks/CU
  gemm_r<0><<<1536, 256, 0, stream>>>(xb, Wqkv_p, b_qkv, Qg, Kg, Vtg, nullptr,
                                      8192, 3072, 1024);
  attn<<<512, 256, 0, stream>>>(Qg, Kg, Vtg, Ao);
  // gemm1: 128x128 tiles, grid 64m x 8n = 512
  gemm_r<1><<<512, 256, 0, stream>>>(Ao, Wout_p, b_out, nullptr, nullptr, nullptr,
                                     out, 8192, 1024, 1024);
}

// Round 18
// 157.920 us; speedup vs baseline: 1.1140x; 1.0136x over previous
//
#include <hip/hip_runtime.h>
#include <stdint.h>

#define B_ 4
#define L_ 2048
#define D_ 1024
#define H_ 16
#define DK_ 64

typedef __attribute__((ext_vector_type(8))) short bf16x8;
typedef __attribute__((ext_vector_type(4))) float f32x4;
typedef unsigned short bfu;   // raw bf16 storage

#define MFMA(a, b, c) __builtin_amdgcn_mfma_f32_16x16x32_bf16((a), (b), (c), 0, 0, 0)

__device__ __forceinline__ unsigned short f2bf(float f) {
  union { float f; unsigned int u; } v; v.f = f;
  unsigned int u = v.u;
  return (unsigned short)((u + 0x7fffu + ((u >> 16) & 1u)) >> 16);  // RNE
}

__device__ __forceinline__ void gll16(const void* g, void* l) {
  __builtin_amdgcn_global_load_lds(
      (const __attribute__((address_space(1))) void*)g,
      (__attribute__((address_space(3))) void*)l, 16, 0, 0);
}

#define VMCNT(n_) asm volatile("s_waitcnt vmcnt(" #n_ ")" ::: "memory")
#define BARRIER() asm volatile("s_barrier" ::: "memory")

// ---------------- prep kernels ----------------

__global__ __launch_bounds__(256) void cast_x(const float* __restrict__ in,
                                              bfu* __restrict__ out, int n4) {
  int i = blockIdx.x * 256 + threadIdx.x;
  if (i >= n4) return;
  float4 v = ((const float4*)in)[i];
  ushort4 o;
  o.x = f2bf(v.x); o.y = f2bf(v.y); o.z = f2bf(v.z); o.w = f2bf(v.w);
  ((ushort4*)out)[i] = o;
}

// W[K][C] fp32 -> B-fragment-packed bf16: block (c>>4, k>>3) of 128 bfu,
// within block (c&15)*8 + (k&7).
__global__ __launch_bounds__(256) void wpack2(const float* __restrict__ in,
                                              bfu* __restrict__ out, int K, int C) {
  int idx = blockIdx.x * 256 + threadIdx.x;
  int c = idx % C, kb = idx / C;
  if (kb >= (K >> 3)) return;
  unsigned short v[8];
#pragma unroll
  for (int j = 0; j < 8; ++j) v[j] = f2bf(in[(size_t)(kb * 8 + j) * C + c]);
  size_t o = ((size_t)(c >> 4) * (K >> 3) + kb) * 128 + (c & 15) * 8;
  *(ushort4*)(out + o) = make_ushort4(v[0], v[1], v[2], v[3]);
  *(ushort4*)(out + o + 4) = make_ushort4(v[4], v[5], v[6], v[7]);
}

// ---------------- reg-B GEMM (round-11 structure, proven 68.2us) ----------
// C[M][N] = A[M][K]*B[K][N], B frag-packed. 256 thr = 4 waves (2m x 2n),
// tile 128x128, per-wave 64x64. A LDS-dbuf via gll16 (1 tile ahead), B in
// named reg buffers brA/brB (2 tiles ahead). Uniform VMCNT(8), one barrier
// per K-tile. Supertile: XCD owns 8-m-tile band, sweeps n.
// EPI 0: scatter Q (log2e/8), K, V (sigma^-1-permuted transpose via LDS).
// EPI 1: fp32 out += bias.

template <int EPI>
__global__ __launch_bounds__(256, 2) void gemm_r(
    const bfu* __restrict__ A, const bfu* __restrict__ Bp,
    const float* __restrict__ bias, bfu* __restrict__ Qg, bfu* __restrict__ Kg,
    bfu* __restrict__ Vtg, float* __restrict__ Out, int M, int N, int K) {
  __shared__ __align__(16) bfu As[2][128 * 64];  // 32 KB total
  const int tid = threadIdx.x;
  const int lane = tid & 63;
  const int w = tid >> 6;
  const int wm = w >> 1, wn = w & 1;
  const int l15 = lane & 15, l4 = lane >> 4;

  const int nwg = gridDim.x;
  const int cpx = nwg >> 3;
  const int bid = (int)blockIdx.x;
  const int swz = (bid & 7) * cpx + (bid >> 3);
  const int NTt = N / 128;
  const int m0 = ((swz & 7) + 8 * (swz / (8 * NTt))) * 128;
  const int n0 = ((swz >> 3) % NTt) * 128;
  const int K8 = K >> 3;

  auto stageA = [&](int t) {
    char* lb = (char*)As[t & 1];
#pragma unroll
    for (int j = 0; j < 4; ++j) {
      int idx = j * 256 + tid;
      int row = idx >> 3, c16p = idx & 7, c16 = c16p ^ (row & 7);
      gll16(A + (size_t)(m0 + row) * K + t * 64 + c16 * 8,
            lb + row * 128 + c16p * 16);
    }
  };

  const size_t bbase = ((size_t)((n0 + wn * 64) >> 4)) * K8;
  auto loadB = [&](int t, bf16x8 (&br)[4][2]) {
#pragma unroll
    for (int ni = 0; ni < 4; ++ni)
#pragma unroll
      for (int kk = 0; kk < 2; ++kk)
        br[ni][kk] = *(const bf16x8*)(
            Bp + (bbase + (size_t)ni * K8 + t * 8 + kk * 4 + l4) * 128 + l15 * 8);
  };

  f32x4 acc[4][4] = {};
  bf16x8 af[4][2], brA[4][2], brB[4][2];

  auto lda = [&](int t) {
    const char* base = (const char*)As[t & 1];
#pragma unroll
    for (int mi = 0; mi < 4; ++mi)
#pragma unroll
      for (int kk = 0; kk < 2; ++kk) {
        int row = wm * 64 + mi * 16 + l15;
        int ch = (kk * 4 + l4) ^ (row & 7);
        af[mi][kk] = *(const bf16x8*)(base + row * 128 + ch * 16);
      }
  };
  auto mm_all = [&](bf16x8 (&br)[4][2]) {
    __builtin_amdgcn_s_setprio(1);
#pragma unroll
    for (int kk = 0; kk < 2; ++kk)
#pragma unroll
      for (int mi = 0; mi < 4; ++mi)
#pragma unroll
        for (int ni = 0; ni < 4; ++ni)
          acc[mi][ni] = MFMA(af[mi][kk], br[ni][kk], acc[mi][ni]);
    __builtin_amdgcn_s_setprio(0);
  };

  const int NT = K >> 6;  // even
  stageA(0);
  __builtin_amdgcn_sched_barrier(0);
  loadB(0, brA);
  loadB(1, brB);

  for (int t = 0; t < NT; t += 2) {
    VMCNT(8); BARRIER();
    lda(t);
    stageA(t + 1);
    __builtin_amdgcn_sched_barrier(0);
    mm_all(brA);
    if (t + 2 < NT) loadB(t + 2, brA);
    if (t + 2 < NT) { VMCNT(8); } else { VMCNT(0); }
    BARRIER();
    lda(t + 1);
    if (t + 2 < NT) stageA(t + 2);
    __builtin_amdgcn_sched_barrier(0);
    mm_all(brB);
    if (t + 3 < NT) loadB(t + 3, brB);
  }

  // ---- epilogue: C/D layout col = lane&15, row = (lane>>4)*4 + reg
  if constexpr (EPI == 1) {
#pragma unroll
    for (int ni = 0; ni < 4; ++ni) {
      int gn = n0 + wn * 64 + ni * 16 + l15;
      float bv = bias[gn];
#pragma unroll
      for (int mi = 0; mi < 4; ++mi)
#pragma unroll
        for (int rg = 0; rg < 4; ++rg) {
          int gm = m0 + wm * 64 + mi * 16 + l4 * 4 + rg;
          Out[(size_t)gm * N + gn] = acc[mi][ni][rg] + bv;
        }
    }
  } else {
    const int sec = n0 >> 10;  // 0 Q, 1 K, 2 V (1024-wide sections)
    if (sec < 2) {
      bfu* dst = (sec == 0) ? Qg : Kg;
      const float scale = (sec == 0) ? 0.18033688011112042f : 1.0f;  // log2e/8
#pragma unroll
      for (int ni = 0; ni < 4; ++ni) {
        int gn = n0 + wn * 64 + ni * 16 + l15;
        int rem = gn & 1023;
        int hh = rem >> 6, dk = rem & 63;
        float bv = bias[gn];
#pragma unroll
        for (int mi = 0; mi < 4; ++mi)
#pragma unroll
          for (int rg = 0; rg < 4; ++rg) {
            int gm = m0 + wm * 64 + mi * 16 + l4 * 4 + rg;
            int bb = gm >> 11, ll = gm & 2047;
            dst[(((size_t)(bb * H_ + hh)) * L_ + ll) * DK_ + dk] =
                f2bf((acc[mi][ni][rg] + bv) * scale);
          }
      }
    } else {
      // V: sigma^-1-permuted transpose via LDS (128n x 128m x 2B = 32 KB)
      __syncthreads();
#pragma unroll
      for (int ni = 0; ni < 4; ++ni) {
        int n_local = wn * 64 + ni * 16 + l15;
        int gn = n0 + n_local;
        float bv = bias[gn];
        int swzn = (n_local & 7) << 4;
#pragma unroll
        for (int mi = 0; mi < 4; ++mi) {
          int m_base = wm * 64 + mi * 16 + l4 * 4;
          int k6 = m_base & 63;
          int p0 = (m_base & ~63) |
                   ((k6 & 32) | (((k6 >> 2) & 3) << 3) | (((k6 >> 4) & 1) << 2));
          float v0 = acc[mi][ni][0] + bv, v1 = acc[mi][ni][1] + bv;
          float v2 = acc[mi][ni][2] + bv, v3 = acc[mi][ni][3] + bv;
          uint32_t w01, w23;
          asm("v_cvt_pk_bf16_f32 %0, %1, %2" : "=v"(w01) : "v"(v0), "v"(v1));
          asm("v_cvt_pk_bf16_f32 %0, %1, %2" : "=v"(w23) : "v"(v2), "v"(v3));
          *(uint32_t*)((char*)As + n_local * 256 + ((2 * p0) ^ swzn)) = w01;
          *(uint32_t*)((char*)As + n_local * 256 + ((2 * p0 + 4) ^ swzn)) = w23;
        }
      }
      __syncthreads();
      int n = tid >> 1;            // 2 threads per n-row
      int cb = (tid & 1) * 8;      // 8 x 16B chunks each
      int gnn = n0 + n;
      int hh = (gnn >> 6) & 15, dk = gnn & 63;
      size_t rowbase =
          (((size_t)((m0 >> 11) * H_ + hh)) * DK_ + dk) * L_ + (m0 & 2047);
#pragma unroll
      for (int j = 0; j < 8; ++j) {
        int ch = cb + j;
        bf16x8 vv = *(const bf16x8*)((char*)As + n * 256 +
                                     ((ch * 16) ^ ((n & 7) << 4)));
        *(bf16x8*)(Vtg + rowbase + ch * 8) = vv;
      }
    }
  }
}

// ---------------- flash attention v8 (causal) ----------------
// = v6 numeric body, but TWO tiles per barrier pair (nt = 2qb+2 always even):
// per pair P: [vmcnt; BAR; compute tiles 2P,2P+1; BAR; stage pair P+2].
// Quad-buffered K/V (slot = t&3, 64 KB LDS, 2 blocks/CU — grid-limited
// anyway). Wait schedule by induction: prologue stages pairs 0,1 + full
// drain; steady queue = {pair P, pair P+1} -> VMCNT(8) retires pair P;
// last iter VMCNT(0). Staging after the trailing barrier makes slot reuse
// race-free. Halves barrier count per tile of work.

__global__ __launch_bounds__(256, 2) void attn(const bfu* __restrict__ Qg,
                                               const bfu* __restrict__ Kg,
                                               const bfu* __restrict__ Vtg,
                                               bfu* __restrict__ Ao) {
  __shared__ __align__(16) bfu Ks[4 * 64 * 64];  // 32 KB
  __shared__ __align__(16) bfu Vs[4 * 64 * 64];  // 32 KB

  const int tid = threadIdx.x;
  const int lane = tid & 63;
  const int w = tid >> 6;
  const int l15 = lane & 15, l4 = lane >> 4;

  const int hid = blockIdx.x;            // 512 blocks
  const int xcd = hid & 7, slot = hid >> 3;
  const int bh = xcd * 8 + (slot >> 3);  // 8 bh per XCD
  const int p = slot & 7;
  const int b = bh >> 4, h = bh & 15;

  for (int seg = 0; seg < 2; ++seg) {
    const int qb = (seg == 0) ? p : 15 - p;   // 128-row superblock
    const int q0 = qb * 128;
    const int nt = 2 * qb + 2;                // even
    const int nP = qb + 1;                    // tile pairs
    const int q0w = q0 + w * 32;              // wave's first q row

    // ---- Q fragments straight from global (Qg pre-scaled by log2e/8)
    bf16x8 qf[2][2];
#pragma unroll
    for (int mi = 0; mi < 2; ++mi)
#pragma unroll
      for (int kk = 0; kk < 2; ++kk)
        qf[mi][kk] = *(const bf16x8*)(
            Qg + ((size_t)bh * L_ + q0w + mi * 16 + l15) * DK_ + kk * 32 + l4 * 8);

    auto stageKV = [&](int tt) {
      const int nb = tt & 3;
      const int nkv = tt * 64;
#pragma unroll
      for (int i = 0; i < 2; ++i) {
        int lb = i * 256 + tid;
        int rr = lb >> 3, c16 = (lb & 7) ^ (rr & 7);
        gll16(Kg + ((size_t)bh * L_ + nkv + rr) * DK_ + c16 * 8,
              (char*)Ks + nb * 8192 + lb * 16);
        gll16(Vtg + ((size_t)bh * DK_ + rr) * L_ + nkv + c16 * 8,
              (char*)Vs + nb * 8192 + lb * 16);
      }
    };

    // ---- prologue: stage pairs 0,1 (tiles 0..3; in-bounds: kv<256<=L) then
    // FULL drain (order-independent; also drains qf + prior-seg stores)
    stageKV(0); stageKV(1); stageKV(2); stageKV(3);
    VMCNT(0);
    BARRIER();

    f32x4 acco[2][4] = {};
    float m[2] = {-1e30f, -1e30f};  // per-lane running max (q = l15)
    float l[2] = {0.f, 0.f};

    for (int P = 0; P < nP; ++P) {
      // pair P ready: steady VMCNT(8) retires pair P (pair P+1 stays in
      // flight); last iter VMCNT(0).
      if (P + 1 < nP) { VMCNT(8); } else { VMCNT(0); }
      BARRIER();

#pragma unroll
      for (int hf = 0; hf < 2; ++hf) {
        const int t = 2 * P + hf;
        const int kv0 = t * 64;
        const char* Kc = (const char*)Ks + (t & 3) * 8192;
        const char* Vc = (const char*)Vs + (t & 3) * 8192;

        if (kv0 <= q0w + 31) {  // wave has unmasked rows in this tile
          // ---- S^T = K Q^T : s[mi][ni][rg] = S^T[kv=ni*16+l4*4+rg][q=l15]
          f32x4 s[2][4] = {};
          __builtin_amdgcn_s_setprio(1);
#pragma unroll
          for (int kk = 0; kk < 2; ++kk)
#pragma unroll
            for (int ni = 0; ni < 4; ++ni) {
              int rr = ni * 16 + l15;
              int ch = (kk * 4 + l4) ^ (rr & 7);
              bf16x8 kf = *(const bf16x8*)(Kc + rr * 128 + ch * 16);
#pragma unroll
              for (int mi = 0; mi < 2; ++mi)
                s[mi][ni] = MFMA(kf, qf[mi][kk], s[mi][ni]);
            }
          __builtin_amdgcn_s_setprio(0);

          if (kv0 + 63 > q0w) {  // diagonal band: mask kv > q
#pragma unroll
            for (int mi = 0; mi < 2; ++mi) {
              int qg_ = q0w + mi * 16 + l15;
#pragma unroll
              for (int ni = 0; ni < 4; ++ni) {
                int kvg = kv0 + ni * 16 + l4 * 4;
#pragma unroll
                for (int rg = 0; rg < 4; ++rg)
                  if (kvg + rg > qg_) s[mi][ni][rg] = -1e30f;
              }
            }
          }

          // ---- row max (max3-shaped tree) + defer-max rescale
          float mx[2];
#pragma unroll
          for (int mi = 0; mi < 2; ++mi) {
            float t1 = fmaxf(fmaxf(s[mi][0][0], s[mi][0][1]), s[mi][0][2]);
            float t2 = fmaxf(fmaxf(s[mi][0][3], s[mi][1][0]), s[mi][1][1]);
            float t3 = fmaxf(fmaxf(s[mi][1][2], s[mi][1][3]), s[mi][2][0]);
            float t4 = fmaxf(fmaxf(s[mi][2][1], s[mi][2][2]), s[mi][2][3]);
            float t5 = fmaxf(fmaxf(s[mi][3][0], s[mi][3][1]), s[mi][3][2]);
            float v = fmaxf(fmaxf(t1, t2), t3);
            v = fmaxf(fmaxf(v, t4), fmaxf(t5, s[mi][3][3]));
            v = fmaxf(v, __shfl_xor(v, 16));
            v = fmaxf(v, __shfl_xor(v, 32));
            mx[mi] = v;
          }
          float grow = fmaxf(mx[0] - m[0], mx[1] - m[1]);
          if (__any(grow > 11.0f)) {
#pragma unroll
            for (int mi = 0; mi < 2; ++mi) {
              float mn = fmaxf(m[mi], mx[mi]);
              float sc = __builtin_amdgcn_exp2f(m[mi] - mn);
              m[mi] = mn;
              l[mi] *= sc;
#pragma unroll
              for (int rg = 0; rg < 4; ++rg) {
                float scq = __shfl(sc, l4 * 4 + rg);
                acco[mi][0][rg] *= scq; acco[mi][1][rg] *= scq;
                acco[mi][2][rg] *= scq; acco[mi][3][rg] *= scq;
              }
            }
          }

          // ---- P = exp2(S^T - m), pack bf16 pairs (kv ascending)
          uint32_t pk[2][4][2];
#pragma unroll
          for (int mi = 0; mi < 2; ++mi)
#pragma unroll
            for (int ni = 0; ni < 4; ++ni) {
              float p0 = __builtin_amdgcn_exp2f(s[mi][ni][0] - m[mi]);
              float p1 = __builtin_amdgcn_exp2f(s[mi][ni][1] - m[mi]);
              float p2 = __builtin_amdgcn_exp2f(s[mi][ni][2] - m[mi]);
              float p3 = __builtin_amdgcn_exp2f(s[mi][ni][3] - m[mi]);
              l[mi] += (p0 + p1) + (p2 + p3);
              asm("v_cvt_pk_bf16_f32 %0, %1, %2" : "=v"(pk[mi][ni][0]) : "v"(p0), "v"(p1));
              asm("v_cvt_pk_bf16_f32 %0, %1, %2" : "=v"(pk[mi][ni][1]) : "v"(p2), "v"(p3));
            }

          // ---- O += P V : pk words ARE the A-frag (V kv-cols pre-permuted)
          __builtin_amdgcn_s_setprio(1);
#pragma unroll
          for (int kk = 0; kk < 2; ++kk) {
            union { uint32_t wd[4]; bf16x8 v; } u[2];
#pragma unroll
            for (int mi = 0; mi < 2; ++mi) {
              u[mi].wd[0] = pk[mi][2 * kk][0];
              u[mi].wd[1] = pk[mi][2 * kk][1];
              u[mi].wd[2] = pk[mi][2 * kk + 1][0];
              u[mi].wd[3] = pk[mi][2 * kk + 1][1];
            }
#pragma unroll
            for (int ni = 0; ni < 4; ++ni) {
              int rr = ni * 16 + l15;
              int ch = (kk * 4 + l4) ^ (rr & 7);
              bf16x8 vf = *(const bf16x8*)(Vc + rr * 128 + ch * 16);
#pragma unroll
              for (int mi = 0; mi < 2; ++mi)
                acco[mi][ni] = MFMA(u[mi].v, vf, acco[mi][ni]);
            }
          }
          __builtin_amdgcn_s_setprio(0);
        }  // active wave for tile t
      }  // hf

      BARRIER();  // all waves done with pair P's buffers
      if (P + 2 < nP) { stageKV(2 * P + 4); stageKV(2 * P + 5); }
    }  // P

    // ---- epilogue: reduce l across l4, redistribute to acco rows, write O
#pragma unroll
    for (int mi = 0; mi < 2; ++mi) {
      float ls = l[mi];
      ls += __shfl_xor(ls, 16);
      ls += __shfl_xor(ls, 32);
      float linv = 1.0f / ls;
#pragma unroll
      for (int rg = 0; rg < 4; ++rg) {
        float lq = __shfl(linv, l4 * 4 + rg);
        int q = q0w + mi * 16 + l4 * 4 + rg;
#pragma unroll
        for (int ni = 0; ni < 4; ++ni) {
          int d = ni * 16 + l15;
          Ao[((size_t)b * L_ + q) * D_ + h * DK_ + d] = f2bf(acco[mi][ni][rg] * lq);
        }
      }
    }
  }  // seg
}

// ---------------- launch ----------------

extern "C" void kernel_launch(void* const* d_in, const int* in_sizes, int n_in,
                              void* d_out, int out_size, void* d_ws, size_t ws_size,
                              hipStream_t stream) {
  const float* x = (const float*)d_in[0];
  const float* W_qkv = (const float*)d_in[1];
  const float* b_qkv = (const float*)d_in[2];
  const float* W_out = (const float*)d_in[3];
  const float* b_out = (const float*)d_in[4];
  float* out = (float*)d_out;

  char* ws = (char*)d_ws;
  bfu* xb     = (bfu*)(ws);                    // 16,777,216
  bfu* Wqkv_p = (bfu*)(ws + 16777216);         //  6,291,456
  bfu* Wout_p = (bfu*)(ws + 23068672);         //  2,097,152
  bfu* Qg     = (bfu*)(ws + 25165824);         // 16,777,216
  bfu* Kg     = (bfu*)(ws + 41943040);         // 16,777,216
  bfu* Vtg    = (bfu*)(ws + 58720256);         // 16,777,216
  bfu* Ao     = (bfu*)(ws + 75497472);         // 16,777,216

  cast_x<<<8192, 256, 0, stream>>>(x, xb, 2097152);
  wpack2<<<1536, 256, 0, stream>>>(W_qkv, Wqkv_p, 1024, 3072);
  wpack2<<<512, 256, 0, stream>>>(W_out, Wout_p, 1024, 1024);

  // gemm0: 128x128 tiles, grid 64m x 24n = 1536, 2 blocks/CU
  gemm_r<0><<<1536, 256, 0, stream>>>(xb, Wqkv_p, b_qkv, Qg, Kg, Vtg, nullptr,
                                      8192, 3072, 1024);
  attn<<<512, 256, 0, stream>>>(Qg, Kg, Vtg, Ao);
  // gemm1: 128x128 tiles, grid 64m x 8n = 512
  gemm_r<1><<<512, 256, 0, stream>>>(Ao, Wout_p, b_out, nullptr, nullptr, nullptr,
                                     out, 8192, 1024, 1024);
}